// Round 6
// baseline (718.475 us; speedup 1.0000x reference)
//
#include <hip/hip_runtime.h>
#include <hip/hip_cooperative_groups.h>
#include <math.h>

namespace cg = cooperative_groups;

#define B_ 8
#define N_ 2048
#define C_ 512
#define G_ 64          // chunks per batch
#define L_ 32          // chunk length = N_/G_

// ---- workspace layout (in floats) ----
static const size_t OFF_V1   = 0;                    // 512
static const size_t OFF_V2   = OFF_V1 + 512;         // 512
static const size_t OFF_S1   = OFF_V2 + 512;         // 16384
static const size_t OFF_S2   = OFF_S1 + 16384;       // 16384
static const size_t OFF_Z    = OFF_S2 + 16384;       // 16384 sorted s2
static const size_t OFF_IDX  = OFF_Z + 16384;        // 16384 perm (int)
static const size_t OFF_P    = OFF_IDX + 16384;      // 16384 p = exp(z-m2)
static const size_t OFF_Q    = OFF_P + 16384;        // 16384 q = exp(0.2(z-m2))
static const size_t OFF_CHP  = OFF_Q + 16384;        // B*G*C = 262144 chunk P sums -> suffix offsets
static const size_t OFF_CHQ  = OFF_CHP + 262144;     // 262144 chunk Q sums -> suffix offsets
static const size_t OFF_TOTQ = OFF_CHQ + 262144;     // 4096 per-(b,c) total Q
static const size_t OFF_EMR  = OFF_TOTQ + 4096;      // 16384 emission row ids (int), bucket order
static const size_t OFF_EMP  = OFF_EMR + 16384;      // 16384 emission fP
static const size_t OFF_EMQ  = OFF_EMP + 16384;      // 16384 emission fQ
static const size_t OFF_POS  = OFF_EMQ + 16384;      // 8*2050 bucket starts (int)

// Single cooperative kernel: 256 blocks x 1024 threads, 1 block/CU, 6 phases.
extern "C" __global__ void __launch_bounds__(1024)
k_mega(const float* __restrict__ x, const float* __restrict__ w,
       const float* __restrict__ a, float* __restrict__ out,
       float* __restrict__ ws)
{
    cg::grid_group grid = cg::this_grid();

    float* v1   = ws + OFF_V1;
    float* v2   = ws + OFF_V2;
    float* s1   = ws + OFF_S1;
    float* s2   = ws + OFF_S2;
    float* zArr = ws + OFF_Z;
    int*   idxA = (int*)(ws + OFF_IDX);
    float* pArr = ws + OFF_P;
    float* qArr = ws + OFF_Q;
    float* chP  = ws + OFF_CHP;
    float* chQ  = ws + OFF_CHQ;
    float* totQ = ws + OFF_TOTQ;
    int*   emR  = (int*)(ws + OFF_EMR);
    float* emP  = ws + OFF_EMP;
    float* emQ  = ws + OFF_EMQ;
    int*   posA = (int*)(ws + OFF_POS);

    int gid = blockIdx.x, tid = threadIdx.x;
    int lane = tid & 63, wid = tid >> 6;

    __shared__ __align__(16) char smraw[43008];   // 42 KB, reused per phase

    // ================= P1: v1 = w@a1, v2 = w@a2 (one wave per row) ==========
    {
        int gw = gid * 16 + wid;                  // 0..4095; 512 active
        if (gw < C_) {
            int row = gw;
            float acc1 = 0.f, acc2 = 0.f;
            #pragma unroll
            for (int i = 0; i < 8; ++i) {
                int c = lane + i * 64;
                float wv = w[row * C_ + c];
                acc1 += wv * a[c];
                acc2 += wv * a[C_ + c];
            }
            for (int o = 32; o > 0; o >>= 1) { acc1 += __shfl_down(acc1, o); acc2 += __shfl_down(acc2, o); }
            if (lane == 0) { v1[row] = acc1; v2[row] = acc2; }
        }
    }
    __threadfence();
    grid.sync();

    // ================= P2: s1[r]=x[r]·v1, s2[r]=x[r]·v2 (wave per row) ======
    {
        float* sv1 = (float*)smraw;               // 512
        float* sv2 = sv1 + C_;                    // 512
        if (tid < C_) sv1[tid] = v1[tid]; else sv2[tid - C_] = v2[tid - C_];
        __syncthreads();
        const float4* w1p = (const float4*)sv1;
        const float4* w2p = (const float4*)sv2;
        #pragma unroll
        for (int rnd = 0; rnd < 4; ++rnd) {
            int r = gid * 64 + rnd * 16 + wid;    // covers 0..16383
            const float4* xr = (const float4*)(x + (size_t)r * C_);
            float a1 = 0.f, a2 = 0.f;
            #pragma unroll
            for (int half = 0; half < 2; ++half) {
                int c4 = lane + half * 64;
                float4 xv = xr[c4], w1 = w1p[c4], w2 = w2p[c4];
                a1 += xv.x*w1.x + xv.y*w1.y + xv.z*w1.z + xv.w*w1.w;
                a2 += xv.x*w2.x + xv.y*w2.y + xv.z*w2.z + xv.w*w2.w;
            }
            for (int o = 32; o > 0; o >>= 1) { a1 += __shfl_down(a1, o); a2 += __shfl_down(a2, o); }
            if (lane == 0) { s1[r] = a1; s2[r] = a2; }
        }
    }
    __threadfence();
    grid.sync();

    // ================= P3: rank-by-counting sort -> z, idx, p, q ============
    {
        struct RankSM { float sval[N_]; int srnk[1024]; float sred[1024]; };
        RankSM* sm = (RankSM*)smraw;
        int b = gid >> 5, grp = gid & 31;
        size_t sb = (size_t)b * N_;
        sm->sval[tid]        = s2[sb + tid];
        sm->sval[tid + 1024] = s2[sb + tid + 1024];
        __syncthreads();
        int le = tid & 63, seg = tid >> 6;        // 16 segments x 128 elems
        int e = grp * 64 + le;
        float val = sm->sval[e];
        int base = seg * 128;
        int rank = 0;
        float mx = -3.4e38f;
        #pragma unroll 8
        for (int i = 0; i < 128; ++i) {
            float v = sm->sval[base + i];
            mx = fmaxf(mx, v);
            rank += (v < val) || (v == val && (base + i) < e);
        }
        sm->srnk[tid] = rank;
        sm->sred[tid] = mx;
        __syncthreads();
        for (int o = 512; o > 0; o >>= 1) {
            if (tid < o) sm->sred[tid] = fmaxf(sm->sred[tid], sm->sred[tid + o]);
            __syncthreads();
        }
        float m2 = sm->sred[0];
        if (tid < 64) {
            int rk = 0;
            #pragma unroll
            for (int s = 0; s < 16; ++s) rk += sm->srnk[s * 64 + tid];
            float vv = sm->sval[grp * 64 + tid];
            float d  = vv - m2;
            size_t pos = sb + rk;
            zArr[pos] = vv;
            idxA[pos] = grp * 64 + tid;
            pArr[pos] = __expf(d);
            qArr[pos] = __expf(0.2f * d);
        }
    }
    __threadfence();
    grid.sync();

    // ================= P4: per-chunk vector sums (2 chunks per block) =======
    {
        struct ChSM { int srow[2][L_]; float spv[2][L_], sqv[2][L_]; };
        ChSM* sm = (ChSM*)smraw;
        int h = tid >> 9, c = tid & 511;
        int job = gid * 2 + h;                    // 0..511
        int b = job >> 6, g = job & 63;
        size_t jb = (size_t)b * N_ + g * L_;
        if (c < L_) {
            sm->srow[h][c] = idxA[jb + c];
            sm->spv[h][c]  = pArr[jb + c];
            sm->sqv[h][c]  = qArr[jb + c];
        }
        __syncthreads();
        const float* xb = x + (size_t)b * N_ * C_;
        float xr_[L_];
        #pragma unroll
        for (int t = 0; t < L_; ++t) xr_[t] = xb[(size_t)sm->srow[h][t] * C_ + c];
        float accP = 0.f, accQ = 0.f;
        #pragma unroll
        for (int t = 0; t < L_; ++t) {
            accP = fmaf(sm->spv[h][t], xr_[t], accP);
            accQ = fmaf(sm->sqv[h][t], xr_[t], accQ);
        }
        chP[(size_t)job * C_ + c] = accP;
        chQ[(size_t)job * C_ + c] = accQ;
    }
    __threadfence();
    grid.sync();

    // ====== P5: blocks 0-7 scalar prep | blocks 8-255 vector suffix scans ===
    if (gid < B_) {
        struct PrepSM {
            float Ppre[N_ + 1], Qpre[N_ + 1], zv[N_];
            int cnt[N_ + 1], ps[N_ + 2];
            float wsP[16], wsQ[16], woP[16], woQ[16];
            int wsC[16], woC[16];
        };
        PrepSM* sm = (PrepSM*)smraw;
        int b = gid;
        size_t ib = (size_t)b * N_;
        for (int i = tid; i < N_ + 1; i += 1024) sm->cnt[i] = 0;
        sm->zv[2*tid]   = zArr[ib + 2*tid];
        sm->zv[2*tid+1] = zArr[ib + 2*tid+1];
        // --- A: scalar exclusive prefixes of p, q ---
        float p0 = pArr[ib + 2*tid], p1 = pArr[ib + 2*tid+1];
        float q0 = qArr[ib + 2*tid], q1 = qArr[ib + 2*tid+1];
        float pv = p0 + p1, qv = q0 + q1, pi = pv, qi = qv;
        for (int o = 1; o < 64; o <<= 1) {
            float tp = __shfl_up(pi, o), tq2 = __shfl_up(qi, o);
            if (lane >= o) { pi += tp; qi += tq2; }
        }
        if (lane == 63) { sm->wsP[wid] = pi; sm->wsQ[wid] = qi; }
        __syncthreads();
        if (wid == 0 && lane < 16) {
            float sp = sm->wsP[lane], sq = sm->wsQ[lane], ip = sp, iq = sq;
            for (int o = 1; o < 16; o <<= 1) {
                float tp = __shfl_up(ip, o), tq2 = __shfl_up(iq, o);
                if (lane >= o) { ip += tp; iq += tq2; }
            }
            sm->woP[lane] = ip - sp; sm->woQ[lane] = iq - sq;
        }
        __syncthreads();
        float inclP = pi + sm->woP[wid], inclQ = qi + sm->woQ[wid];
        float exclP = inclP - pv, exclQ = inclQ - qv;
        sm->Ppre[2*tid] = exclP; sm->Ppre[2*tid+1] = exclP + p0;
        sm->Qpre[2*tid] = exclQ; sm->Qpre[2*tid+1] = exclQ + q0;
        if (tid == 1023) { sm->Ppre[N_] = inclP; sm->Qpre[N_] = inclQ; }
        __syncthreads();
        // --- C: per-row split + factors + bucket count ---
        float m2 = sm->zv[N_ - 1], Ptot = sm->Ppre[N_];
        int kk[2], sl[2]; float fPv[2], fQv[2];
        #pragma unroll
        for (int h2 = 0; h2 < 2; ++h2) {
            int rl = tid + h2 * 1024;
            float s1v = s1[ib + rl], thr = -s1v;
            int lo = 0, hi = N_;
            while (lo < hi) { int mid = (lo + hi) >> 1; if (sm->zv[mid] >= thr) hi = mid; else lo = mid + 1; }
            float beta = s1v + m2, wPc, wQc;
            if (beta >= 0.f) { wPc = 1.f;                 wQc = __expf(-0.8f * beta); }
            else             { wPc = __expf(0.8f * beta); wQc = 1.f; }
            float inv = 1.f / (wPc * (Ptot - sm->Ppre[lo]) + wQc * sm->Qpre[lo]);
            fPv[h2] = wPc * inv; fQv[h2] = wQc * inv; kk[h2] = lo;
            sl[h2] = atomicAdd(&sm->cnt[lo], 1);
        }
        __syncthreads();
        // --- D: scan bucket counts -> ps ---
        int c0 = sm->cnt[2*tid], c1 = sm->cnt[2*tid+1], cv = c0 + c1, ci = cv;
        for (int o = 1; o < 64; o <<= 1) { int t2 = __shfl_up(ci, o); if (lane >= o) ci += t2; }
        if (lane == 63) sm->wsC[wid] = ci;
        __syncthreads();
        if (wid == 0 && lane < 16) {
            int sc = sm->wsC[lane], ic = sc;
            for (int o = 1; o < 16; o <<= 1) { int t2 = __shfl_up(ic, o); if (lane >= o) ic += t2; }
            sm->woC[lane] = ic - sc;
        }
        __syncthreads();
        int inclC = ci + sm->woC[wid], exclC = inclC - cv;
        sm->ps[2*tid] = exclC; sm->ps[2*tid+1] = exclC + c0;
        if (tid == 1023) { sm->ps[N_] = inclC; sm->ps[N_+1] = inclC + sm->cnt[N_]; }
        __syncthreads();
        posA[b * 2050 + tid]        = sm->ps[tid];
        posA[b * 2050 + 1024 + tid] = sm->ps[1024 + tid];
        if (tid < 2) posA[b * 2050 + 2048 + tid] = sm->ps[2048 + tid];
        // --- E: scatter emission records in bucket order ---
        #pragma unroll
        for (int h2 = 0; h2 < 2; ++h2) {
            int rl = tid + h2 * 1024;
            int u = sm->ps[kk[h2]] + sl[h2];
            emR[ib + u] = rl; emP[ib + u] = fPv[h2]; emQ[ib + u] = fQv[h2];
        }
    } else {
        // P5a: exclusive SUFFIX offsets of chP/chQ + totQ, wave per (arr,b,c)
        int wgw = (gid - B_) * 16 + wid;          // 0..3967
        for (int t = wgw; t < 2 * B_ * C_; t += (256 - B_) * 16) {
            int isQ = t >> 12;                     // 4096 tasks per array
            int rem = t & 4095;
            int b = rem >> 9, c = rem & 511;
            float* arr = isQ ? chQ : chP;
            size_t id0 = ((size_t)(b * G_ + lane)) * C_ + c;
            float val = arr[id0];
            float incl = val;
            #pragma unroll
            for (int o = 1; o < 64; o <<= 1) {
                float tmp = __shfl(incl, (lane + o) & 63);
                if (lane + o < 64) incl += tmp;
            }
            arr[id0] = incl - val;                 // sum over g' > lane
            if (isQ && lane == 0) totQ[b * C_ + c] = incl;
        }
    }
    __threadfence();
    grid.sync();

    // ================= P6: fused suffix walk + output emission ==============
    {
        struct FuseSM {
            int srow[2][L_]; float spv[2][L_], sqv[2][L_];
            int sps[2][L_ + 2];
            int semRow[N_]; float semFP[N_], semFQ[N_];
        };
        FuseSM* sm = (FuseSM*)smraw;
        int h = tid >> 9, c = tid & 511;
        int job = gid * 2 + h;                    // both halves share b
        int b = job >> 6, g = job & 63;
        size_t ib = (size_t)b * N_;
        size_t jb = ib + g * L_;
        if (c < L_) {
            sm->srow[h][c] = idxA[jb + c];
            sm->spv[h][c]  = pArr[jb + c];
            sm->sqv[h][c]  = qArr[jb + c];
        }
        if (c < L_ + 2) sm->sps[h][c] = posA[b * 2050 + g * L_ + c];
        __syncthreads();
        int uS0    = sm->sps[0][0];
        int n0     = sm->sps[0][L_] - uS0;        // half0 never has g==63
        int uStart = sm->sps[h][0];
        int uEnd   = (g == 63) ? sm->sps[h][L_ + 1] : sm->sps[h][L_];
        int offH   = h ? n0 : 0;
        for (int u = uStart + c; u < uEnd; u += 512) {
            int e = offH + (u - uStart);
            sm->semRow[e] = emR[ib + u];
            sm->semFP[e]  = emP[ib + u];
            sm->semFQ[e]  = emQ[ib + u];
        }
        __syncthreads();
        const float* xb = x + (size_t)b * N_ * C_;
        float*       ob = out + (size_t)b * N_ * C_;
        float xr_[L_];
        #pragma unroll
        for (int t = 0; t < L_; ++t) xr_[t] = xb[(size_t)sm->srow[h][t] * C_ + c];
        float runP = chP[(size_t)job * C_ + c];
        float runQ = chQ[(size_t)job * C_ + c];
        float tq   = totQ[b * C_ + c];
        if (g == 63) {                             // bucket k == N
            for (int u = sm->sps[h][L_]; u < sm->sps[h][L_ + 1]; ++u) {
                int e = offH + (u - uStart);
                ob[(size_t)sm->semRow[e] * C_ + c] = sm->semFP[e] * runP + sm->semFQ[e] * (tq - runQ);
            }
        }
        #pragma unroll
        for (int t = L_ - 1; t >= 0; --t) {
            runP = fmaf(sm->spv[h][t], xr_[t], runP);
            runQ = fmaf(sm->sqv[h][t], xr_[t], runQ);
            for (int u = sm->sps[h][t]; u < sm->sps[h][t + 1]; ++u) {
                int e = offH + (u - uStart);
                ob[(size_t)sm->semRow[e] * C_ + c] = sm->semFP[e] * runP + sm->semFQ[e] * (tq - runQ);
            }
        }
    }
}

extern "C" void kernel_launch(void* const* d_in, const int* in_sizes, int n_in,
                              void* d_out, int out_size, void* d_ws, size_t ws_size,
                              hipStream_t stream) {
    const float* x = (const float*)d_in[0];
    const float* w = (const float*)d_in[1];
    const float* a = (const float*)d_in[2];
    float* out = (float*)d_out;
    float* ws  = (float*)d_ws;

    void* args[] = { (void*)&x, (void*)&w, (void*)&a, (void*)&out, (void*)&ws };
    hipLaunchCooperativeKernel((const void*)k_mega, dim3(256), dim3(1024),
                               args, 0, stream);
}

// Round 8
// 132.962 us; speedup vs baseline: 5.4036x; 5.4036x over previous
//
#include <hip/hip_runtime.h>
#include <math.h>

#define B_ 8
#define N_ 2048
#define C_ 512
#define G_ 64          // chunks per batch
#define L_ 32          // chunk length = N_/G_

// ---- workspace layout (in floats) ----
static const size_t OFF_V1   = 0;                    // 512
static const size_t OFF_V2   = OFF_V1 + 512;         // 512
static const size_t OFF_S1   = OFF_V2 + 512;         // 16384
static const size_t OFF_S2   = OFF_S1 + 16384;       // 16384
static const size_t OFF_Z    = OFF_S2 + 16384;       // 16384 sorted s2
static const size_t OFF_IDX  = OFF_Z + 16384;        // 16384 perm (int)
static const size_t OFF_P    = OFF_IDX + 16384;      // 16384 p = exp(z-m2)
static const size_t OFF_Q    = OFF_P + 16384;        // 16384 q = exp(0.2(z-m2))
static const size_t OFF_CHP  = OFF_Q + 16384;        // B*G*C = 262144 chunk P sums -> suffix offsets
static const size_t OFF_CHQ  = OFF_CHP + 262144;     // 262144 chunk Q sums -> suffix offsets
static const size_t OFF_TOTQ = OFF_CHQ + 262144;     // 4096 per-(b,c) total Q
static const size_t OFF_EMR  = OFF_TOTQ + 4096;      // 16384 emission row ids (int), bucket order
static const size_t OFF_EMP  = OFF_EMR + 16384;      // 16384 emission fP
static const size_t OFF_EMQ  = OFF_EMP + 16384;      // 16384 emission fQ
static const size_t OFF_POS  = OFF_EMQ + 16384;      // 8*2050 bucket starts (int)

// ---- float4 helpers ----
__device__ inline float4 f4z() { return make_float4(0.f, 0.f, 0.f, 0.f); }
__device__ inline float4 fma4(float s, float4 a, float4 c) {
    c.x = fmaf(s, a.x, c.x); c.y = fmaf(s, a.y, c.y);
    c.z = fmaf(s, a.z, c.z); c.w = fmaf(s, a.w, c.w); return c;
}
__device__ inline float4 add4(float4 a, float4 b) {
    return make_float4(a.x + b.x, a.y + b.y, a.z + b.z, a.w + b.w);
}
// fp*P + fq*(T - Q)
__device__ inline float4 comb4(float fp, float4 P, float fq, float4 T, float4 Q) {
    return make_float4(fp * P.x + fq * (T.x - Q.x),
                       fp * P.y + fq * (T.y - Q.y),
                       fp * P.z + fq * (T.z - Q.z),
                       fp * P.w + fq * (T.w - Q.w));
}

// K1: v1 = w @ a1, v2 = w @ a2
__global__ __launch_bounds__(64) void k_wa(const float* __restrict__ w,
                                           const float* __restrict__ a,
                                           float* __restrict__ v1, float* __restrict__ v2) {
    int k = blockIdx.x, lane = threadIdx.x;
    float acc1 = 0.f, acc2 = 0.f;
    for (int c = lane; c < C_; c += 64) {
        float wv = w[k * C_ + c];
        acc1 += wv * a[c];
        acc2 += wv * a[C_ + c];
    }
    for (int o = 32; o > 0; o >>= 1) { acc1 += __shfl_down(acc1, o); acc2 += __shfl_down(acc2, o); }
    if (lane == 0) { v1[k] = acc1; v2[k] = acc2; }
}

// K2: s1[r] = x[r,:]·v1, s2[r] = x[r,:]·v2
__global__ __launch_bounds__(256) void k_s(const float* __restrict__ x,
                                           const float* __restrict__ v1,
                                           const float* __restrict__ v2,
                                           float* __restrict__ s1, float* __restrict__ s2) {
    __shared__ __align__(16) float sv1[C_];
    __shared__ __align__(16) float sv2[C_];
    int tid = threadIdx.x;
    for (int c = tid; c < C_; c += 256) { sv1[c] = v1[c]; sv2[c] = v2[c]; }
    __syncthreads();
    int wave = tid >> 6, lane = tid & 63;
    int r = blockIdx.x * 4 + wave;
    const float4* xr  = reinterpret_cast<const float4*>(x + (size_t)r * C_);
    const float4* w1p = reinterpret_cast<const float4*>(sv1);
    const float4* w2p = reinterpret_cast<const float4*>(sv2);
    float a1 = 0.f, a2 = 0.f;
    #pragma unroll
    for (int half = 0; half < 2; ++half) {
        int c4 = lane + half * 64;
        float4 xv = xr[c4], w1 = w1p[c4], w2 = w2p[c4];
        a1 += xv.x*w1.x + xv.y*w1.y + xv.z*w1.z + xv.w*w1.w;
        a2 += xv.x*w2.x + xv.y*w2.y + xv.z*w2.z + xv.w*w2.w;
    }
    for (int o = 32; o > 0; o >>= 1) { a1 += __shfl_down(a1, o); a2 += __shfl_down(a2, o); }
    if (lane == 0) { s1[r] = a1; s2[r] = a2; }
}

// K3: rank-by-counting sort of s2 -> z (sorted), idx (perm), p, q
__global__ __launch_bounds__(256) void k_rank(const float* __restrict__ s2,
                                              float* __restrict__ z, int* __restrict__ idxArr,
                                              float* __restrict__ pArr, float* __restrict__ qArr) {
    __shared__ float sval[N_];
    __shared__ float sred[256];
    __shared__ int   srnk[256];
    int blk = blockIdx.x;
    int b = blk >> 5, grp = blk & 31;
    int tid = threadIdx.x;
    int le = tid & 63, qtr = tid >> 6;
    for (int i = tid; i < N_; i += 256) sval[i] = s2[(size_t)b * N_ + i];
    __syncthreads();
    int e = grp * 64 + le;
    float val = sval[e];
    int base = qtr * 512;
    int rank = 0;
    float mx = -3.4e38f;
    #pragma unroll 8
    for (int i = 0; i < 512; ++i) {
        int t = base + i;
        float v = sval[t];
        mx = fmaxf(mx, v);
        rank += (v < val) || (v == val && t < e);
    }
    srnk[tid] = rank;
    sred[tid] = mx;
    __syncthreads();
    for (int o = 128; o > 0; o >>= 1) {
        if (tid < o) sred[tid] = fmaxf(sred[tid], sred[tid + o]);
        __syncthreads();
    }
    float m2 = sred[0];
    if (qtr == 0) {
        int rk = srnk[le] + srnk[le + 64] + srnk[le + 128] + srnk[le + 192];
        float d = val - m2;
        size_t pos = (size_t)b * N_ + rk;
        z[pos]      = val;
        idxArr[pos] = e;
        pArr[pos]   = __expf(d);
        qArr[pos]   = __expf(0.2f * d);
    }
}

// K4: per-chunk vector sums chP/chQ[b,g,:] — float4 gathers, 4 row-groups + LDS reduce
__global__ __launch_bounds__(512) void k_chunk(const float* __restrict__ x,
                                               const int* __restrict__ idxArr,
                                               const float* __restrict__ pArr,
                                               const float* __restrict__ qArr,
                                               float* __restrict__ chP, float* __restrict__ chQ) {
    int bg = blockIdx.x, b = bg >> 6, g = bg & 63;
    int tid = threadIdx.x;
    __shared__ int   srow[L_];
    __shared__ float spv[L_], sqv[L_];
    __shared__ float4 partP[4][128], partQ[4][128];
    if (tid < L_) {
        int j = g * L_ + tid;
        srow[tid] = idxArr[b * N_ + j];
        spv[tid]  = pArr[b * N_ + j];
        sqv[tid]  = qArr[b * N_ + j];
    }
    __syncthreads();
    int rg = tid >> 7, q = tid & 127;
    const float4* xb4 = reinterpret_cast<const float4*>(x + (size_t)b * N_ * C_);
    float4 aP = f4z(), aQ = f4z();
    #pragma unroll
    for (int i = 0; i < 8; ++i) {
        int j = rg * 8 + i;
        float4 xv = xb4[(size_t)srow[j] * 128 + q];
        aP = fma4(spv[j], xv, aP);
        aQ = fma4(sqv[j], xv, aQ);
    }
    partP[rg][q] = aP;
    partQ[rg][q] = aQ;
    __syncthreads();
    if (tid < 128) {
        float4 s = add4(add4(partP[0][tid], partP[1][tid]), add4(partP[2][tid], partP[3][tid]));
        reinterpret_cast<float4*>(chP + (size_t)bg * C_)[tid] = s;
    } else if (tid < 256) {
        int qq = tid - 128;
        float4 s = add4(add4(partQ[0][qq], partQ[1][qq]), add4(partQ[2][qq], partQ[3][qq]));
        reinterpret_cast<float4*>(chQ + (size_t)bg * C_)[qq] = s;
    }
}

// K5: chunk sums -> exclusive SUFFIX offsets in place + totQ. One thread per (arr,b,c).
__global__ __launch_bounds__(128) void k_choff(float* __restrict__ chP, float* __restrict__ chQ,
                                               float* __restrict__ totQ) {
    int t = blockIdx.x * 128 + threadIdx.x;   // 0..8191
    int isQ = t >> 12, rem = t & 4095;
    int b = rem >> 9, c = rem & 511;
    float* arr = isQ ? chQ : chP;
    float v[G_];
    #pragma unroll
    for (int g = 0; g < G_; ++g)
        v[g] = arr[((size_t)(b * G_ + g)) * C_ + c];
    float run = 0.f;
    #pragma unroll
    for (int g = G_ - 1; g >= 0; --g) {
        float tv = v[g];
        arr[((size_t)(b * G_ + g)) * C_ + c] = run;
        run += tv;
    }
    if (isQ) totQ[b * C_ + c] = run;
}

// K6: per-batch prep (one block per batch, 1024 threads):
//  A) scalar exclusive prefixes of p,q (LDS only)
//  C) per output row: binary search split k, factors fP/fQ, bucket count
//  D) scan bucket counts -> posStart
//  E) scatter emission records (row, fP, fQ) in bucket order
__global__ __launch_bounds__(1024) void k_prep(const float* __restrict__ s1,
                                               const float* __restrict__ z,
                                               const float* __restrict__ pArr,
                                               const float* __restrict__ qArr,
                                               int* __restrict__ emRow,
                                               float* __restrict__ emFP,
                                               float* __restrict__ emFQ,
                                               int* __restrict__ posStart) {
    __shared__ float Ppre[2049], Qpre[2049];
    __shared__ float zv[N_];
    __shared__ int   cnt[2049];
    __shared__ int   ps[2050];
    __shared__ float wsP[16], wsQ[16], woP[16], woQ[16];
    __shared__ int   wsC[16], woC[16];
    int b = blockIdx.x, tid = threadIdx.x, lane = tid & 63, wid = tid >> 6;
    size_t ib = (size_t)b * N_;

    for (int i = tid; i < 2049; i += 1024) cnt[i] = 0;
    zv[2*tid]   = z[ib + 2*tid];
    zv[2*tid+1] = z[ib + 2*tid+1];

    // --- A: scalar scans of p and q ---
    float p0 = pArr[ib + 2*tid], p1 = pArr[ib + 2*tid+1];
    float q0 = qArr[ib + 2*tid], q1 = qArr[ib + 2*tid+1];
    float pv = p0 + p1, qv = q0 + q1;
    float pi = pv, qi = qv;
    for (int o = 1; o < 64; o <<= 1) {
        float tp = __shfl_up(pi, o), tq2 = __shfl_up(qi, o);
        if (lane >= o) { pi += tp; qi += tq2; }
    }
    if (lane == 63) { wsP[wid] = pi; wsQ[wid] = qi; }
    __syncthreads();
    if (wid == 0 && lane < 16) {
        float sp = wsP[lane], sq = wsQ[lane];
        float ip = sp, iq = sq;
        for (int o = 1; o < 16; o <<= 1) {
            float tp = __shfl_up(ip, o), tq2 = __shfl_up(iq, o);
            if (lane >= o) { ip += tp; iq += tq2; }
        }
        woP[lane] = ip - sp; woQ[lane] = iq - sq;
    }
    __syncthreads();
    float inclP = pi + woP[wid], inclQ = qi + woQ[wid];
    float exclP = inclP - pv,    exclQ = inclQ - qv;
    Ppre[2*tid]   = exclP;  Ppre[2*tid+1] = exclP + p0;
    Qpre[2*tid]   = exclQ;  Qpre[2*tid+1] = exclQ + q0;
    if (tid == 1023) { Ppre[2048] = inclP; Qpre[2048] = inclQ; }
    __syncthreads();

    // --- C: per-row split + factors + bucket count ---
    float m2   = zv[N_ - 1];
    float Ptot = Ppre[2048];
    int   kk[2], sl[2];
    float fPv[2], fQv[2];
    #pragma unroll
    for (int h = 0; h < 2; ++h) {
        int rl = tid + h * 1024;
        float s1v = s1[ib + rl];
        float thr = -s1v;
        int lo = 0, hi = N_;
        while (lo < hi) { int mid = (lo + hi) >> 1; if (zv[mid] >= thr) hi = mid; else lo = mid + 1; }
        float beta = s1v + m2;
        float wPc, wQc;
        if (beta >= 0.f) { wPc = 1.f;                  wQc = __expf(-0.8f * beta); }
        else             { wPc = __expf(0.8f * beta);  wQc = 1.f; }
        float Sp = Ptot - Ppre[lo];
        float Sq = Qpre[lo];
        float inv = 1.f / (wPc * Sp + wQc * Sq);
        fPv[h] = wPc * inv;
        fQv[h] = wQc * inv;
        kk[h] = lo;
        sl[h] = atomicAdd(&cnt[lo], 1);
    }
    __syncthreads();

    // --- D: scan of cnt[0..2047] (+ bucket 2048 appended) ---
    int c0 = cnt[2*tid], c1 = cnt[2*tid+1];
    int cv = c0 + c1, ci = cv;
    for (int o = 1; o < 64; o <<= 1) {
        int t2 = __shfl_up(ci, o);
        if (lane >= o) ci += t2;
    }
    if (lane == 63) wsC[wid] = ci;
    __syncthreads();
    if (wid == 0 && lane < 16) {
        int sc = wsC[lane], ic = sc;
        for (int o = 1; o < 16; o <<= 1) { int t2 = __shfl_up(ic, o); if (lane >= o) ic += t2; }
        woC[lane] = ic - sc;
    }
    __syncthreads();
    int inclC = ci + woC[wid];
    int exclC = inclC - cv;
    ps[2*tid] = exclC; ps[2*tid+1] = exclC + c0;
    if (tid == 1023) { ps[2048] = inclC; ps[2049] = inclC + cnt[2048]; }
    __syncthreads();
    posStart[b * 2050 + tid]        = ps[tid];
    posStart[b * 2050 + 1024 + tid] = ps[1024 + tid];
    if (tid < 2) posStart[b * 2050 + 2048 + tid] = ps[2048 + tid];
    // --- E: scatter emission records in bucket order ---
    #pragma unroll
    for (int h = 0; h < 2; ++h) {
        int rl = tid + h * 1024;
        int u  = ps[kk[h]] + sl[h];
        emRow[ib + u] = rl;
        emFP [ib + u] = fPv[h];
        emFQ [ib + u] = fQv[h];
    }
}

// K7: fused suffix walk + output emission. 4 row-groups x 128 threads x float4;
// groups compute partials, derive offsets via LDS, walk concurrently.
__global__ __launch_bounds__(512) void k_fused(const float* __restrict__ x,
                                               const int* __restrict__ idxArr,
                                               const float* __restrict__ pArr,
                                               const float* __restrict__ qArr,
                                               const float* __restrict__ chP,
                                               const float* __restrict__ chQ,
                                               const float* __restrict__ totQ,
                                               const int* __restrict__ emRow,
                                               const float* __restrict__ emFP,
                                               const float* __restrict__ emFQ,
                                               const int* __restrict__ posStart,
                                               float* __restrict__ out) {
    int bg = blockIdx.x, b = bg >> 6, g = bg & 63;
    int tid = threadIdx.x;
    __shared__ int   srow[L_];
    __shared__ float spv[L_], sqv[L_];
    __shared__ int   sps[L_ + 2];
    __shared__ int   semRow[N_];
    __shared__ float semFP[N_], semFQ[N_];
    __shared__ float4 partP[4][128], partQ[4][128];
    if (tid < L_) {
        int j = g * L_ + tid;
        srow[tid] = idxArr[b * N_ + j];
        spv[tid]  = pArr[b * N_ + j];
        sqv[tid]  = qArr[b * N_ + j];
    }
    if (tid >= 64 && tid < 64 + L_ + 2) sps[tid - 64] = posStart[b * 2050 + g * L_ + (tid - 64)];
    __syncthreads();
    int uStart = sps[0];
    int uEnd   = (g == G_ - 1) ? sps[L_ + 1] : sps[L_];
    size_t ib = (size_t)b * N_;
    for (int u = uStart + tid; u < uEnd; u += 512) {
        int e = u - uStart;
        semRow[e] = emRow[ib + u];
        semFP[e]  = emFP [ib + u];
        semFQ[e]  = emFQ [ib + u];
    }
    int rg = tid >> 7, q = tid & 127;
    const float4* xb4 = reinterpret_cast<const float4*>(x + (size_t)b * N_ * C_);
    float4 xr4[8];
    #pragma unroll
    for (int i = 0; i < 8; ++i)
        xr4[i] = xb4[(size_t)srow[rg * 8 + i] * 128 + q];
    float4 sP = f4z(), sQ = f4z();
    #pragma unroll
    for (int i = 0; i < 8; ++i) {
        int j = rg * 8 + i;
        sP = fma4(spv[j], xr4[i], sP);
        sQ = fma4(sqv[j], xr4[i], sQ);
    }
    partP[rg][q] = sP;
    partQ[rg][q] = sQ;
    __syncthreads();
    // group offsets = chunk suffix offset + partials of later groups
    float4 runP = reinterpret_cast<const float4*>(chP + (size_t)bg * C_)[q];
    float4 runQ = reinterpret_cast<const float4*>(chQ + (size_t)bg * C_)[q];
    float4 tq4  = reinterpret_cast<const float4*>(totQ + (size_t)b * C_)[q];
    #pragma unroll
    for (int rg2 = 3; rg2 >= 1; --rg2) {
        if (rg2 > rg) { runP = add4(runP, partP[rg2][q]); runQ = add4(runQ, partQ[rg2][q]); }
    }
    float4* ob4 = reinterpret_cast<float4*>(out + (size_t)b * N_ * C_);
    if (g == G_ - 1 && rg == 3) {
        // bucket k == N: SufP = 0 (runP = chunk offset = 0), PreQ = totQ
        for (int u = sps[L_]; u < sps[L_ + 1]; ++u) {
            int e = u - uStart;
            ob4[(size_t)semRow[e] * 128 + q] = comb4(semFP[e], runP, semFQ[e], tq4, runQ);
        }
    }
    #pragma unroll
    for (int t = 7; t >= 0; --t) {
        int j = rg * 8 + t;
        runP = fma4(spv[j], xr4[t], runP);
        runQ = fma4(sqv[j], xr4[t], runQ);
        for (int u = sps[j]; u < sps[j + 1]; ++u) {
            int e = u - uStart;
            ob4[(size_t)semRow[e] * 128 + q] = comb4(semFP[e], runP, semFQ[e], tq4, runQ);
        }
    }
}

extern "C" void kernel_launch(void* const* d_in, const int* in_sizes, int n_in,
                              void* d_out, int out_size, void* d_ws, size_t ws_size,
                              hipStream_t stream) {
    const float* x = (const float*)d_in[0];
    const float* w = (const float*)d_in[1];
    const float* a = (const float*)d_in[2];
    float* out = (float*)d_out;
    float* ws  = (float*)d_ws;

    float* v1   = ws + OFF_V1;
    float* v2   = ws + OFF_V2;
    float* s1   = ws + OFF_S1;
    float* s2   = ws + OFF_S2;
    float* zArr = ws + OFF_Z;
    int*   idxA = (int*)(ws + OFF_IDX);
    float* pArr = ws + OFF_P;
    float* qArr = ws + OFF_Q;
    float* chP  = ws + OFF_CHP;
    float* chQ  = ws + OFF_CHQ;
    float* totQ = ws + OFF_TOTQ;
    int*   emR  = (int*)(ws + OFF_EMR);
    float* emP  = ws + OFF_EMP;
    float* emQ  = ws + OFF_EMQ;
    int*   pos  = (int*)(ws + OFF_POS);

    k_wa   <<<dim3(C_),      dim3(64),   0, stream>>>(w, a, v1, v2);
    k_s    <<<dim3(4096),    dim3(256),  0, stream>>>(x, v1, v2, s1, s2);
    k_rank <<<dim3(B_ * 32), dim3(256),  0, stream>>>(s2, zArr, idxA, pArr, qArr);
    k_chunk<<<dim3(B_ * G_), dim3(512),  0, stream>>>(x, idxA, pArr, qArr, chP, chQ);
    k_choff<<<dim3(64),      dim3(128),  0, stream>>>(chP, chQ, totQ);
    k_prep <<<dim3(B_),      dim3(1024), 0, stream>>>(s1, zArr, pArr, qArr, emR, emP, emQ, pos);
    k_fused<<<dim3(B_ * G_), dim3(512),  0, stream>>>(x, idxA, pArr, qArr, chP, chQ, totQ,
                                                      emR, emP, emQ, pos, out);
}